// Round 1
// baseline (589.516 us; speedup 1.0000x reference)
//
#include <hip/hip_runtime.h>
#include <hip/hip_bf16.h>

#define N_ 16
#define L_ 256
#define C_ 512
#define HW_ 1024
#define HEADS_ 16
#define DH_ 32

typedef unsigned short u16;
typedef unsigned int u32;

__device__ __forceinline__ float bs2f(u32 u) {
    union { u32 i; float f; } x; x.i = u << 16; return x.f;
}
__device__ __forceinline__ u16 f2bs(float f) {
    union { float f; u32 i; } x; x.f = f;
    u32 r = x.i + 0x7fffu + ((x.i >> 16) & 1u);
    return (u16)(r >> 16);
}

// ---------------------------------------------------------------------------
// proj_kv: K/V 1x1-conv projections as one GEMM pair.
//   Kout[m][no] = sum_c token[m][c] * wk[no][c] + bk[no]   (m = n*L + l)
//   Vout likewise. Output bf16, layout [N*L][C].
// 64x64 tile, 256 threads, 4x4 per-thread register block, fp32 accumulate.
// ---------------------------------------------------------------------------
__global__ __launch_bounds__(256) void proj_kv_kernel(
    const float* __restrict__ token,
    const float* __restrict__ wk, const float* __restrict__ bk,
    const float* __restrict__ wv, const float* __restrict__ bv,
    u16* __restrict__ Kout, u16* __restrict__ Vout)
{
    __shared__ __align__(16) float As[16][68];
    __shared__ __align__(16) float Bks[16][68];
    __shared__ __align__(16) float Bvs[16][68];
    const int t = threadIdx.x;
    const int tx = t & 15, ty = t >> 4;
    const int m0 = blockIdx.x * 64;
    const int n0 = blockIdx.y * 64;

    float ak[4][4] = {{0.f}}, av[4][4] = {{0.f}};

    for (int c0 = 0; c0 < C_; c0 += 16) {
        const int cc = t & 15;
        const int r0 = t >> 4;
        #pragma unroll
        for (int p = 0; p < 4; ++p) {
            const int r = r0 + 16 * p;
            As[cc][r]  = token[(size_t)(m0 + r) * C_ + c0 + cc];
            Bks[cc][r] = wk[(size_t)(n0 + r) * C_ + c0 + cc];
            Bvs[cc][r] = wv[(size_t)(n0 + r) * C_ + c0 + cc];
        }
        __syncthreads();
        #pragma unroll
        for (int kk = 0; kk < 16; ++kk) {
            float4 a4 = *(const float4*)&As[kk][ty * 4];
            float4 k4 = *(const float4*)&Bks[kk][tx * 4];
            float4 v4 = *(const float4*)&Bvs[kk][tx * 4];
            const float aa[4] = {a4.x, a4.y, a4.z, a4.w};
            const float kb[4] = {k4.x, k4.y, k4.z, k4.w};
            const float vb[4] = {v4.x, v4.y, v4.z, v4.w};
            #pragma unroll
            for (int i = 0; i < 4; ++i) {
                #pragma unroll
                for (int j = 0; j < 4; ++j) {
                    ak[i][j] += aa[i] * kb[j];
                    av[i][j] += aa[i] * vb[j];
                }
            }
        }
        __syncthreads();
    }
    float4 bk4 = *(const float4*)&bk[n0 + tx * 4];
    float4 bv4 = *(const float4*)&bv[n0 + tx * 4];
    const float bkv[4] = {bk4.x, bk4.y, bk4.z, bk4.w};
    const float bvv[4] = {bv4.x, bv4.y, bv4.z, bv4.w};
    #pragma unroll
    for (int i = 0; i < 4; ++i) {
        ushort4 kw, vw;
        kw.x = f2bs(ak[i][0] + bkv[0]); kw.y = f2bs(ak[i][1] + bkv[1]);
        kw.z = f2bs(ak[i][2] + bkv[2]); kw.w = f2bs(ak[i][3] + bkv[3]);
        vw.x = f2bs(av[i][0] + bvv[0]); vw.y = f2bs(av[i][1] + bvv[1]);
        vw.z = f2bs(av[i][2] + bvv[2]); vw.w = f2bs(av[i][3] + bvv[3]);
        const size_t o = (size_t)(m0 + ty * 4 + i) * C_ + n0 + tx * 4;
        *(ushort4*)&Kout[o] = kw;
        *(ushort4*)&Vout[o] = vw;
    }
}

// ---------------------------------------------------------------------------
// proj_q: Q projection.  Qout[m][no] = sum_c feature[n][c][pos]*wq[no][c]+bq,
//   m = n*HW + pos.  Output bf16, layout [N*HW][C].
// ---------------------------------------------------------------------------
__global__ __launch_bounds__(256) void proj_q_kernel(
    const float* __restrict__ feature,
    const float* __restrict__ wq, const float* __restrict__ bq,
    u16* __restrict__ Qout)
{
    __shared__ __align__(16) float As[16][68];
    __shared__ __align__(16) float Bs[16][68];
    const int t = threadIdx.x;
    const int tx = t & 15, ty = t >> 4;
    const int m0 = blockIdx.x * 64;
    const int n0 = blockIdx.y * 64;
    const int n = m0 >> 10;
    const int pos0 = m0 & (HW_ - 1);

    float acc[4][4] = {{0.f}};

    for (int c0 = 0; c0 < C_; c0 += 16) {
        {
            const int r = t & 63;
            const int cb = t >> 6;
            #pragma unroll
            for (int p = 0; p < 4; ++p) {
                const int cc = cb * 4 + p;
                As[cc][r] = feature[((size_t)n * C_ + c0 + cc) * HW_ + pos0 + r];
            }
            const int cc = t & 15;
            const int r0 = t >> 4;
            #pragma unroll
            for (int p = 0; p < 4; ++p) {
                const int r2 = r0 + 16 * p;
                Bs[cc][r2] = wq[(size_t)(n0 + r2) * C_ + c0 + cc];
            }
        }
        __syncthreads();
        #pragma unroll
        for (int kk = 0; kk < 16; ++kk) {
            float4 a4 = *(const float4*)&As[kk][ty * 4];
            float4 b4 = *(const float4*)&Bs[kk][tx * 4];
            const float aa[4] = {a4.x, a4.y, a4.z, a4.w};
            const float bb[4] = {b4.x, b4.y, b4.z, b4.w};
            #pragma unroll
            for (int i = 0; i < 4; ++i) {
                #pragma unroll
                for (int j = 0; j < 4; ++j)
                    acc[i][j] += aa[i] * bb[j];
            }
        }
        __syncthreads();
    }
    float4 bq4 = *(const float4*)&bq[n0 + tx * 4];
    const float bqv[4] = {bq4.x, bq4.y, bq4.z, bq4.w};
    #pragma unroll
    for (int i = 0; i < 4; ++i) {
        ushort4 w;
        w.x = f2bs(acc[i][0] + bqv[0]); w.y = f2bs(acc[i][1] + bqv[1]);
        w.z = f2bs(acc[i][2] + bqv[2]); w.w = f2bs(acc[i][3] + bqv[3]);
        const size_t o = (size_t)(m0 + ty * 4 + i) * C_ + n0 + tx * 4;
        *(ushort4*)&Qout[o] = w;
    }
}

// ---------------------------------------------------------------------------
// attn: per (pos-tile 64, head, batch) block.
//   scores(64x256) = Q(64x32) K^T -> softmax rows -> proj(64x32) = P V
//   out = feature + proj (transposed through LDS for coalesced stores).
// LDS: Qh/Kh bf16 [32][72] (9.2KB, aliased later by pp), Sh bf16 [64][264]
// (33KB), Vh bf16 [256][34] (17KB) -> 59KB total.
// ---------------------------------------------------------------------------
__global__ __launch_bounds__(256) void attn_kernel(
    const u16* __restrict__ Qws, const u16* __restrict__ Kws,
    const u16* __restrict__ Vws, const float* __restrict__ feature,
    float* __restrict__ out)
{
    __shared__ __align__(16) unsigned char smem[9216 + 33792 + 17408];
    u16 (*Qh)[72]  = (u16(*)[72])(smem);
    u16 (*Kh)[72]  = (u16(*)[72])(smem + 4608);
    u16 (*Sh)[264] = (u16(*)[264])(smem + 9216);
    u16 (*Vh)[34]  = (u16(*)[34])(smem + 9216 + 33792);
    float (*pp)[33] = (float(*)[33])(smem);   // aliases Qh/Kh (dead after scores)

    const int t = threadIdx.x;
    const int pt = blockIdx.x;
    const int h  = blockIdx.y;
    const int n  = blockIdx.z;
    const int pos0 = pt * 64;
    const size_t qbase  = ((size_t)n * HW_ + pos0) * C_ + h * DH_;
    const size_t kvbase = ((size_t)n * L_) * C_ + h * DH_;

    // Q tile -> Qh[d][r]
    {
        const int d = t & 31, r0 = t >> 5;
        #pragma unroll
        for (int p = 0; p < 8; ++p) {
            const int r = r0 + 8 * p;
            Qh[d][r] = Qws[qbase + (size_t)r * C_ + d];
        }
    }
    // V -> Vh[l][dv] (uint = 2 bf16 at a time)
    {
        const int dp = t & 15, li = t >> 4;
        #pragma unroll
        for (int p = 0; p < 16; ++p) {
            const int l = li + 16 * p;
            const u32 u = *(const u32*)&Vws[kvbase + (size_t)l * C_ + dp * 2];
            *(u32*)&Vh[l][dp * 2] = u;
        }
    }

    const int tx = t & 15, ty = t >> 4;
    const float inv_scale = 0.17677669529663687f;  // 1/sqrt(32)

    // scores in 4 chunks of 64 l
    for (int chk = 0; chk < 4; ++chk) {
        const int l0 = chk * 64;
        {
            const int d = t & 31, lc0 = t >> 5;
            #pragma unroll
            for (int p = 0; p < 8; ++p) {
                const int lc = lc0 + 8 * p;
                Kh[d][lc] = Kws[kvbase + (size_t)(l0 + lc) * C_ + d];
            }
        }
        __syncthreads();
        float acc[4][4] = {{0.f}};
        #pragma unroll
        for (int kk = 0; kk < 32; ++kk) {
            ushort4 qa = *(const ushort4*)&Qh[kk][ty * 4];
            ushort4 kb = *(const ushort4*)&Kh[kk][tx * 4];
            const float aa[4] = {bs2f(qa.x), bs2f(qa.y), bs2f(qa.z), bs2f(qa.w)};
            const float bb[4] = {bs2f(kb.x), bs2f(kb.y), bs2f(kb.z), bs2f(kb.w)};
            #pragma unroll
            for (int i = 0; i < 4; ++i) {
                #pragma unroll
                for (int j = 0; j < 4; ++j)
                    acc[i][j] += aa[i] * bb[j];
            }
        }
        #pragma unroll
        for (int i = 0; i < 4; ++i) {
            ushort4 w;
            w.x = f2bs(acc[i][0] * inv_scale);
            w.y = f2bs(acc[i][1] * inv_scale);
            w.z = f2bs(acc[i][2] * inv_scale);
            w.w = f2bs(acc[i][3] * inv_scale);
            *(ushort4*)&Sh[ty * 4 + i][l0 + tx * 4] = w;
        }
        __syncthreads();
    }

    // softmax: each wave owns 16 rows, full-wave reduction per row
    {
        const int lane = t & 63, wid = t >> 6;
        for (int rr = 0; rr < 16; ++rr) {
            const int r = wid * 16 + rr;
            float v[4];
            #pragma unroll
            for (int p = 0; p < 4; ++p) v[p] = bs2f(Sh[r][lane + 64 * p]);
            float m = fmaxf(fmaxf(v[0], v[1]), fmaxf(v[2], v[3]));
            #pragma unroll
            for (int off = 32; off >= 1; off >>= 1) m = fmaxf(m, __shfl_xor(m, off));
            float e[4], s = 0.f;
            #pragma unroll
            for (int p = 0; p < 4; ++p) { e[p] = __expf(v[p] - m); s += e[p]; }
            #pragma unroll
            for (int off = 32; off >= 1; off >>= 1) s += __shfl_xor(s, off);
            const float inv = 1.0f / s;
            #pragma unroll
            for (int p = 0; p < 4; ++p) Sh[r][lane + 64 * p] = f2bs(e[p] * inv);
        }
    }
    __syncthreads();

    // PV: proj[r][c] = sum_l P[r][l] V[l][c]; thread tile 4 rows x 2 cols
    {
        const int tx2 = t & 15, ty2 = t >> 4;
        const int c = tx2 * 2;
        float acc2[4][2] = {{0.f}};
        for (int kk0 = 0; kk0 < 256; kk0 += 4) {
            float vbq[4][2];
            #pragma unroll
            for (int q = 0; q < 4; ++q) {
                const u32 u = *(const u32*)&Vh[kk0 + q][c];
                vbq[q][0] = bs2f(u & 0xffffu);
                vbq[q][1] = bs2f(u >> 16);
            }
            #pragma unroll
            for (int i = 0; i < 4; ++i) {
                ushort4 s4 = *(const ushort4*)&Sh[ty2 * 4 + i][kk0];
                const float sv[4] = {bs2f(s4.x), bs2f(s4.y), bs2f(s4.z), bs2f(s4.w)};
                #pragma unroll
                for (int q = 0; q < 4; ++q) {
                    acc2[i][0] += sv[q] * vbq[q][0];
                    acc2[i][1] += sv[q] * vbq[q][1];
                }
            }
        }
        // all threads are past Qh/Kh reads (softmax barrier) -> pp may alias
        #pragma unroll
        for (int i = 0; i < 4; ++i) {
            pp[ty2 * 4 + i][c]     = acc2[i][0];
            pp[ty2 * 4 + i][c + 1] = acc2[i][1];
        }
    }
    __syncthreads();

    // epilogue: out[n][h*32+dv][pos0+r] = feature + proj, coalesced over r
    #pragma unroll
    for (int it = 0; it < 8; ++it) {
        const int e = it * 256 + t;
        const int dv = e >> 6, r = e & 63;
        const size_t o = ((size_t)n * C_ + h * DH_ + dv) * HW_ + pos0 + r;
        out[o] = feature[o] + pp[r][dv];
    }
}

extern "C" void kernel_launch(void* const* d_in, const int* in_sizes, int n_in,
                              void* d_out, int out_size, void* d_ws, size_t ws_size,
                              hipStream_t stream)
{
    const float* feature = (const float*)d_in[0];
    const float* token   = (const float*)d_in[1];
    const float* wq      = (const float*)d_in[2];
    const float* bq      = (const float*)d_in[3];
    const float* wk      = (const float*)d_in[4];
    const float* bk      = (const float*)d_in[5];
    const float* wv      = (const float*)d_in[6];
    const float* bv      = (const float*)d_in[7];
    float* out = (float*)d_out;

    // workspace: Q [N*HW][C] bf16, K [N*L][C] bf16, V [N*L][C] bf16 (~25 MB)
    u16* Qws = (u16*)d_ws;
    u16* Kws = Qws + (size_t)N_ * HW_ * C_;
    u16* Vws = Kws + (size_t)N_ * L_ * C_;

    proj_q_kernel<<<dim3(256, 8, 1), 256, 0, stream>>>(feature, wq, bq, Qws);
    proj_kv_kernel<<<dim3(64, 8, 1), 256, 0, stream>>>(token, wk, bk, wv, bv, Kws, Vws);
    attn_kernel<<<dim3(16, 16, 16), 256, 0, stream>>>(Qws, Kws, Vws, feature, out);
}

// Round 2
// 249.799 us; speedup vs baseline: 2.3600x; 2.3600x over previous
//
#include <hip/hip_runtime.h>
#include <hip/hip_bf16.h>

#define N_ 16
#define L_ 256
#define C_ 512
#define HW_ 1024
#define HEADS_ 16
#define DH_ 32

typedef unsigned short u16;
typedef unsigned int u32;
typedef __attribute__((ext_vector_type(8))) short short8_t;
typedef __attribute__((ext_vector_type(4))) float f32x4;

__device__ __forceinline__ float bs2f(u32 u) {
    union { u32 i; float f; } x; x.i = u << 16; return x.f;
}
__device__ __forceinline__ u16 f2bs(float f) {
    union { float f; u32 i; } x; x.f = f;
    u32 r = x.i + 0x7fffu + ((x.i >> 16) & 1u);
    return (u16)(r >> 16);
}

// ---------------------------------------------------------------------------
// proj_kv: K/V 1x1-conv projections as one GEMM pair (fp32 VALU, unchanged
// structure). K stored [n*L+l][C] bf16. V stored TRANSPOSED [n][dout][l] bf16
// (reference's natural 'ndl' layout) so attn PV B-frags are contiguous.
// ---------------------------------------------------------------------------
__global__ __launch_bounds__(256) void proj_kv_kernel(
    const float* __restrict__ token,
    const float* __restrict__ wk, const float* __restrict__ bk,
    const float* __restrict__ wv, const float* __restrict__ bv,
    u16* __restrict__ Kout, u16* __restrict__ Vout)
{
    __shared__ __align__(16) float As[16][68];
    __shared__ __align__(16) float Bks[16][68];
    __shared__ __align__(16) float Bvs[16][68];
    const int t = threadIdx.x;
    const int tx = t & 15, ty = t >> 4;
    const int m0 = blockIdx.x * 64;
    const int n0 = blockIdx.y * 64;

    float ak[4][4] = {{0.f}}, av[4][4] = {{0.f}};

    for (int c0 = 0; c0 < C_; c0 += 16) {
        const int cc = t & 15;
        const int r0 = t >> 4;
        #pragma unroll
        for (int p = 0; p < 4; ++p) {
            const int r = r0 + 16 * p;
            As[cc][r]  = token[(size_t)(m0 + r) * C_ + c0 + cc];
            Bks[cc][r] = wk[(size_t)(n0 + r) * C_ + c0 + cc];
            Bvs[cc][r] = wv[(size_t)(n0 + r) * C_ + c0 + cc];
        }
        __syncthreads();
        #pragma unroll
        for (int kk = 0; kk < 16; ++kk) {
            float4 a4 = *(const float4*)&As[kk][ty * 4];
            float4 k4 = *(const float4*)&Bks[kk][tx * 4];
            float4 v4 = *(const float4*)&Bvs[kk][tx * 4];
            const float aa[4] = {a4.x, a4.y, a4.z, a4.w};
            const float kb[4] = {k4.x, k4.y, k4.z, k4.w};
            const float vb[4] = {v4.x, v4.y, v4.z, v4.w};
            #pragma unroll
            for (int i = 0; i < 4; ++i) {
                #pragma unroll
                for (int j = 0; j < 4; ++j) {
                    ak[i][j] += aa[i] * kb[j];
                    av[i][j] += aa[i] * vb[j];
                }
            }
        }
        __syncthreads();
    }
    float4 bk4 = *(const float4*)&bk[n0 + tx * 4];
    float4 bv4 = *(const float4*)&bv[n0 + tx * 4];
    const float bkv[4] = {bk4.x, bk4.y, bk4.z, bk4.w};
    const float bvv[4] = {bv4.x, bv4.y, bv4.z, bv4.w};
    const int n  = m0 >> 8;        // L = 256 rows per batch, tile stays inside one n
    const int l0 = m0 & 255;
    const size_t vtbase = (size_t)n * C_ * L_;
    #pragma unroll
    for (int i = 0; i < 4; ++i) {
        ushort4 kw;
        kw.x = f2bs(ak[i][0] + bkv[0]); kw.y = f2bs(ak[i][1] + bkv[1]);
        kw.z = f2bs(ak[i][2] + bkv[2]); kw.w = f2bs(ak[i][3] + bkv[3]);
        const size_t o = (size_t)(m0 + ty * 4 + i) * C_ + n0 + tx * 4;
        *(ushort4*)&Kout[o] = kw;
        #pragma unroll
        for (int j = 0; j < 4; ++j) {
            Vout[vtbase + (size_t)(n0 + tx * 4 + j) * L_ + l0 + ty * 4 + i] =
                f2bs(av[i][j] + bvv[j]);
        }
    }
}

// ---------------------------------------------------------------------------
// proj_q: Q projection (fp32 VALU, unchanged). Output bf16 [N*HW][C].
// ---------------------------------------------------------------------------
__global__ __launch_bounds__(256) void proj_q_kernel(
    const float* __restrict__ feature,
    const float* __restrict__ wq, const float* __restrict__ bq,
    u16* __restrict__ Qout)
{
    __shared__ __align__(16) float As[16][68];
    __shared__ __align__(16) float Bs[16][68];
    const int t = threadIdx.x;
    const int tx = t & 15, ty = t >> 4;
    const int m0 = blockIdx.x * 64;
    const int n0 = blockIdx.y * 64;
    const int n = m0 >> 10;
    const int pos0 = m0 & (HW_ - 1);

    float acc[4][4] = {{0.f}};

    for (int c0 = 0; c0 < C_; c0 += 16) {
        {
            const int r = t & 63;
            const int cb = t >> 6;
            #pragma unroll
            for (int p = 0; p < 4; ++p) {
                const int cc = cb * 4 + p;
                As[cc][r] = feature[((size_t)n * C_ + c0 + cc) * HW_ + pos0 + r];
            }
            const int cc = t & 15;
            const int r0 = t >> 4;
            #pragma unroll
            for (int p = 0; p < 4; ++p) {
                const int r2 = r0 + 16 * p;
                Bs[cc][r2] = wq[(size_t)(n0 + r2) * C_ + c0 + cc];
            }
        }
        __syncthreads();
        #pragma unroll
        for (int kk = 0; kk < 16; ++kk) {
            float4 a4 = *(const float4*)&As[kk][ty * 4];
            float4 b4 = *(const float4*)&Bs[kk][tx * 4];
            const float aa[4] = {a4.x, a4.y, a4.z, a4.w};
            const float bb[4] = {b4.x, b4.y, b4.z, b4.w};
            #pragma unroll
            for (int i = 0; i < 4; ++i) {
                #pragma unroll
                for (int j = 0; j < 4; ++j)
                    acc[i][j] += aa[i] * bb[j];
            }
        }
        __syncthreads();
    }
    float4 bq4 = *(const float4*)&bq[n0 + tx * 4];
    const float bqv[4] = {bq4.x, bq4.y, bq4.z, bq4.w};
    #pragma unroll
    for (int i = 0; i < 4; ++i) {
        ushort4 w;
        w.x = f2bs(acc[i][0] + bqv[0]); w.y = f2bs(acc[i][1] + bqv[1]);
        w.z = f2bs(acc[i][2] + bqv[2]); w.w = f2bs(acc[i][3] + bqv[3]);
        const size_t o = (size_t)(m0 + ty * 4 + i) * C_ + n0 + tx * 4;
        *(ushort4*)&Qout[o] = w;
    }
}

// ---------------------------------------------------------------------------
// attn (MFMA): block = (64 q-rows, head, batch), 4 waves, each wave owns 16
// q-rows. QK^T via mfma_16x16x32 (single K-step, d=32), in-register softmax
// (16 frags in-lane + 4x shfl_xor over the 16-lane column group), P->LDS
// bf16, PV via MFMA (A=P from LDS, B=V^T staged [d][l]), epilogue transposed
// through LDS for coalesced feature+proj stores.
// LDS: Q[64][40] 5.1K | K[256][40] 20K | Vt[32][264] 16.9K | P[64][264] 33.8K
//      = 74.5K (2 blocks/CU). po[32][66] f32 aliases Q/K (dead regions).
// ---------------------------------------------------------------------------
__global__ __launch_bounds__(256) void attn_kernel(
    const u16* __restrict__ Qws, const u16* __restrict__ Kws,
    const u16* __restrict__ Vws, const float* __restrict__ feature,
    float* __restrict__ out)
{
    __shared__ __align__(16) unsigned char smem[76288];
    u16 (*Qh)[40]   = (u16(*)[40])(smem);            //     0 .. 5119
    u16 (*Kh)[40]   = (u16(*)[40])(smem + 5120);     //  5120 .. 25599
    u16 (*Vt)[264]  = (u16(*)[264])(smem + 25600);   // 25600 .. 42495
    u16 (*Ph)[264]  = (u16(*)[264])(smem + 42496);   // 42496 .. 76287
    float (*po)[66] = (float(*)[66])(smem);          // 8448 B, aliases Q/K

    const int t = threadIdx.x;
    const int pt = blockIdx.x;
    const int h  = blockIdx.y;
    const int n  = blockIdx.z;
    const int pos0 = pt * 64;
    const size_t qbase = ((size_t)n * HW_ + pos0) * C_ + h * DH_;
    const size_t kbase = ((size_t)n * L_) * C_ + h * DH_;
    const size_t vbase = (size_t)n * C_ * L_ + (size_t)h * DH_ * L_;

    // ---- stage Q (64 x 32), K (256 x 32), V^T (32 x 256) ----
    {
        const int row = t >> 2, ch = t & 3;
        *(short8_t*)&Qh[row][ch * 8] =
            *(const short8_t*)&Qws[qbase + (size_t)row * C_ + ch * 8];
        #pragma unroll
        for (int p = 0; p < 4; ++p) {
            const int r = row + 64 * p;
            *(short8_t*)&Kh[r][ch * 8] =
                *(const short8_t*)&Kws[kbase + (size_t)r * C_ + ch * 8];
        }
        #pragma unroll
        for (int p = 0; p < 4; ++p) {
            const int idx = p * 256 + t;
            const int d = idx >> 5, c = idx & 31;
            *(short8_t*)&Vt[d][c * 8] =
                *(const short8_t*)&Vws[vbase + (size_t)d * L_ + c * 8];
        }
    }
    __syncthreads();

    const int wid = t >> 6, lane = t & 63;
    const int g = lane >> 4, i16 = lane & 15;
    const float inv_scale = 0.17677669529663687f;  // 1/sqrt(32)

    // ---- QK^T: wave owns 16 q-rows x 256 l ----
    f32x4 s[16];
    {
        short8_t a = *(const short8_t*)&Qh[wid * 16 + i16][g * 8];
        #pragma unroll
        for (int nf = 0; nf < 16; ++nf) {
            short8_t b = *(const short8_t*)&Kh[nf * 16 + i16][g * 8];
            f32x4 z = {0.f, 0.f, 0.f, 0.f};
            s[nf] = __builtin_amdgcn_mfma_f32_16x16x32_bf16(a, b, z, 0, 0, 0);
        }
    }

    // ---- softmax over l (rows q = wid*16 + g*4 + r) ----
    float mx[4], inv[4];
    #pragma unroll
    for (int r = 0; r < 4; ++r) {
        float m = s[0][r];
        #pragma unroll
        for (int nf = 1; nf < 16; ++nf) m = fmaxf(m, s[nf][r]);
        #pragma unroll
        for (int off = 8; off >= 1; off >>= 1) m = fmaxf(m, __shfl_xor(m, off));
        mx[r] = m;
    }
    #pragma unroll
    for (int r = 0; r < 4; ++r) {
        float ss = 0.f;
        #pragma unroll
        for (int nf = 0; nf < 16; ++nf) {
            float e = __expf((s[nf][r] - mx[r]) * inv_scale);
            s[nf][r] = e;
            ss += e;
        }
        #pragma unroll
        for (int off = 8; off >= 1; off >>= 1) ss += __shfl_xor(ss, off);
        inv[r] = 1.0f / ss;
    }
    #pragma unroll
    for (int r = 0; r < 4; ++r) {
        const int q = wid * 16 + g * 4 + r;
        #pragma unroll
        for (int nf = 0; nf < 16; ++nf)
            Ph[q][nf * 16 + i16] = f2bs(s[nf][r] * inv[r]);
    }
    __syncthreads();

    // ---- PV: O[16 q][32 d] per wave, K-dim = 256 l ----
    f32x4 o0 = {0.f, 0.f, 0.f, 0.f}, o1 = {0.f, 0.f, 0.f, 0.f};
    #pragma unroll
    for (int ks = 0; ks < 8; ++ks) {
        short8_t pa  = *(const short8_t*)&Ph[wid * 16 + i16][ks * 32 + g * 8];
        short8_t vb0 = *(const short8_t*)&Vt[i16][ks * 32 + g * 8];
        short8_t vb1 = *(const short8_t*)&Vt[16 + i16][ks * 32 + g * 8];
        o0 = __builtin_amdgcn_mfma_f32_16x16x32_bf16(pa, vb0, o0, 0, 0, 0);
        o1 = __builtin_amdgcn_mfma_f32_16x16x32_bf16(pa, vb1, o1, 0, 0, 0);
    }
    // po[d][q] (aliases Q/K — every wave is past all Q/K reads: the
    // post-softmax barrier dominates; po doesn't overlap Vt/Ph)
    #pragma unroll
    for (int r = 0; r < 4; ++r) {
        const int q = wid * 16 + g * 4 + r;
        po[i16][q]      = o0[r];
        po[16 + i16][q] = o1[r];
    }
    __syncthreads();

    // ---- epilogue: out[n][h*32+d][pos0+q] = feature + proj, coalesced ----
    #pragma unroll
    for (int p = 0; p < 8; ++p) {
        const int e = p * 256 + t;
        const int d = e >> 6, q = e & 63;
        const size_t o = ((size_t)n * C_ + h * DH_ + d) * HW_ + pos0 + q;
        out[o] = feature[o] + po[d][q];
    }
}

extern "C" void kernel_launch(void* const* d_in, const int* in_sizes, int n_in,
                              void* d_out, int out_size, void* d_ws, size_t ws_size,
                              hipStream_t stream)
{
    const float* feature = (const float*)d_in[0];
    const float* token   = (const float*)d_in[1];
    const float* wq      = (const float*)d_in[2];
    const float* bq      = (const float*)d_in[3];
    const float* wk      = (const float*)d_in[4];
    const float* bk      = (const float*)d_in[5];
    const float* wv      = (const float*)d_in[6];
    const float* bv      = (const float*)d_in[7];
    float* out = (float*)d_out;

    // workspace: Q [N*HW][C] bf16, K [N*L][C] bf16, V^T [N][C][L] bf16 (~24 MB)
    u16* Qws = (u16*)d_ws;
    u16* Kws = Qws + (size_t)N_ * HW_ * C_;
    u16* Vws = Kws + (size_t)N_ * L_ * C_;

    proj_q_kernel<<<dim3(256, 8, 1), 256, 0, stream>>>(feature, wq, bq, Qws);
    proj_kv_kernel<<<dim3(64, 8, 1), 256, 0, stream>>>(token, wk, bk, wv, bv, Kws, Vws);
    attn_kernel<<<dim3(16, 16, 16), 256, 0, stream>>>(Qws, Kws, Vws, feature, out);
}

// Round 3
// 89.595 us; speedup vs baseline: 6.5798x; 2.7881x over previous
//
#include <hip/hip_runtime.h>
#include <hip/hip_bf16.h>

#define N_ 16
#define L_ 256
#define C_ 512
#define HW_ 1024
#define HEADS_ 16
#define DH_ 32

typedef unsigned short u16;
typedef unsigned int u32;
typedef __attribute__((ext_vector_type(8))) short short8_t;
typedef __attribute__((ext_vector_type(4))) float f32x4;

__device__ __forceinline__ float bs2f(u32 u) {
    union { u32 i; float f; } x; x.i = u << 16; return x.f;
}
__device__ __forceinline__ u16 f2bs(float f) {
    union { float f; u32 i; } x; x.f = f;
    u32 r = x.i + 0x7fffu + ((x.i >> 16) & 1u);
    return (u16)(r >> 16);
}

// ---------------------------------------------------------------------------
// prep: flat fp32->bf16 converts: token (524288 f4), wq/wk/wv (65536 f4 each).
// Grid = 2816 blocks x 256 thr, one float4 per thread.
// ---------------------------------------------------------------------------
__global__ __launch_bounds__(256) void prep_kernel(
    const float* __restrict__ token, const float* __restrict__ wq,
    const float* __restrict__ wk, const float* __restrict__ wv,
    u16* __restrict__ tokb, u16* __restrict__ wqb,
    u16* __restrict__ wkb, u16* __restrict__ wvb)
{
    const int idx = blockIdx.x * 256 + threadIdx.x;
    const float* s; u16* d; int off;
    if (idx < 524288)            { s = token; d = tokb; off = idx; }
    else if (idx < 524288+65536) { s = wq; d = wqb; off = idx - 524288; }
    else if (idx < 524288+131072){ s = wk; d = wkb; off = idx - 524288 - 65536; }
    else                         { s = wv; d = wvb; off = idx - 524288 - 131072; }
    float4 v = ((const float4*)s)[off];
    ushort4 w;
    w.x = f2bs(v.x); w.y = f2bs(v.y); w.z = f2bs(v.z); w.w = f2bs(v.w);
    ((ushort4*)d)[off] = w;
}

// ---------------------------------------------------------------------------
// transpose_f: feature [n][c][pos] f32 -> Ft [(n*HW+pos)][c] bf16.
// 64x64 tile via LDS (pitch 67 f32: column reads conflict-free, 67%32=3).
// ---------------------------------------------------------------------------
__global__ __launch_bounds__(256) void transpose_f_kernel(
    const float* __restrict__ feature, u16* __restrict__ Ft)
{
    __shared__ float LT[64][67];
    const int t = threadIdx.x;
    const int pb = blockIdx.x, cb = blockIdx.y, n = blockIdx.z;
    const int c0 = cb * 64, pos0 = pb * 64;

    #pragma unroll
    for (int r = 0; r < 4; ++r) {
        const int c = r * 16 + (t >> 4);
        const int p = (t & 15) * 4;
        float4 v = *(const float4*)&feature[((size_t)n * C_ + c0 + c) * HW_ + pos0 + p];
        LT[c][p] = v.x; LT[c][p+1] = v.y; LT[c][p+2] = v.z; LT[c][p+3] = v.w;
    }
    __syncthreads();
    #pragma unroll
    for (int rep = 0; rep < 2; ++rep) {
        const int pos = (t >> 3) + rep * 32;
        const int c = (t & 7) * 8;
        u16 tmp[8];
        #pragma unroll
        for (int j = 0; j < 8; ++j) tmp[j] = f2bs(LT[c + j][pos]);
        *(short8_t*)&Ft[(size_t)(n * HW_ + pos0 + pos) * C_ + c0 + c] =
            *(short8_t*)tmp;
    }
}

// ---------------------------------------------------------------------------
// gemm_q (MFMA): Out[m][dout] = sum_c A[m][c]*W[dout][c] + bias[dout].
// BM=BN=BK=64, 256 thr / 4 waves (2x2), XOR-swizzled LDS granules (8 shorts)
// so staging ds_write_b128 and frag ds_read_b128 are conflict-free.
// Epilogue bounces through LDS (pitch 72) for coalesced short8 stores.
// ---------------------------------------------------------------------------
__global__ __launch_bounds__(256) void gemm_q_kernel(
    const u16* __restrict__ A, const u16* __restrict__ Wb,
    const float* __restrict__ bias, u16* __restrict__ Out)
{
    __shared__ __align__(16) unsigned char smem[16384];
    u16* As = (u16*)smem;            // [64][64] swizzled
    u16* Bs = (u16*)(smem + 8192);   // [64][64] swizzled
    u16 (*LTo)[72] = (u16(*)[72])smem;  // epilogue, 9216 B

    const int t = threadIdx.x;
    const int m0 = blockIdx.x * 64, n0 = blockIdx.y * 64;
    const int lane = t & 63, wid = t >> 6;
    const int i16 = lane & 15, g = lane >> 4;
    const int wm = wid >> 1, wn = wid & 1;
    const int row_a = t >> 3, c8 = t & 7;

    f32x4 acc[2][2] = {{{0.f,0.f,0.f,0.f},{0.f,0.f,0.f,0.f}},
                       {{0.f,0.f,0.f,0.f},{0.f,0.f,0.f,0.f}}};
    const float b0 = bias[n0 + wn * 32 + i16];
    const float b1 = bias[n0 + wn * 32 + 16 + i16];

    for (int c0 = 0; c0 < C_; c0 += 64) {
        __syncthreads();
        #pragma unroll
        for (int r = 0; r < 2; ++r) {
            const int m = row_a + r * 32;
            short8_t va = *(const short8_t*)&A[(size_t)(m0 + m) * C_ + c0 + c8 * 8];
            *(short8_t*)&As[m * 64 + ((c8 ^ (m & 7)) << 3)] = va;
            short8_t vb = *(const short8_t*)&Wb[(size_t)(n0 + m) * C_ + c0 + c8 * 8];
            *(short8_t*)&Bs[m * 64 + ((c8 ^ (m & 7)) << 3)] = vb;
        }
        __syncthreads();
        #pragma unroll
        for (int ks = 0; ks < 2; ++ks) {
            short8_t a[2], b[2];
            #pragma unroll
            for (int mt = 0; mt < 2; ++mt) {
                const int m = wm * 32 + mt * 16 + i16;
                a[mt] = *(const short8_t*)&As[m * 64 + ((((ks << 2) | g) ^ (m & 7)) << 3)];
            }
            #pragma unroll
            for (int nt = 0; nt < 2; ++nt) {
                const int d = wn * 32 + nt * 16 + i16;
                b[nt] = *(const short8_t*)&Bs[d * 64 + ((((ks << 2) | g) ^ (d & 7)) << 3)];
            }
            #pragma unroll
            for (int mt = 0; mt < 2; ++mt)
                #pragma unroll
                for (int nt = 0; nt < 2; ++nt)
                    acc[mt][nt] = __builtin_amdgcn_mfma_f32_16x16x32_bf16(
                        a[mt], b[nt], acc[mt][nt], 0, 0, 0);
        }
    }
    __syncthreads();
    #pragma unroll
    for (int mt = 0; mt < 2; ++mt)
        #pragma unroll
        for (int nt = 0; nt < 2; ++nt) {
            const float bb = nt ? b1 : b0;
            #pragma unroll
            for (int r = 0; r < 4; ++r)
                LTo[wm * 32 + mt * 16 + g * 4 + r][wn * 32 + nt * 16 + i16] =
                    f2bs(acc[mt][nt][r] + bb);
        }
    __syncthreads();
    #pragma unroll
    for (int rep = 0; rep < 2; ++rep) {
        const int m = (t >> 3) + rep * 32;
        const int cs = (t & 7) * 8;
        *(short8_t*)&Out[(size_t)(m0 + m) * C_ + n0 + cs] = *(short8_t*)&LTo[m][cs];
    }
}

// ---------------------------------------------------------------------------
// gemm_kv (MFMA): A = token bf16 [nb*L+l][C]; K row-major out (LDS bounce),
// V transposed out [nb][dout][l] (direct ushort4, l-contiguous).
// ---------------------------------------------------------------------------
__global__ __launch_bounds__(256) void gemm_kv_kernel(
    const u16* __restrict__ A, const u16* __restrict__ Wkb,
    const u16* __restrict__ Wvb, const float* __restrict__ bk,
    const float* __restrict__ bv, u16* __restrict__ Kout, u16* __restrict__ Vt)
{
    __shared__ __align__(16) unsigned char smem[24576];
    u16* As  = (u16*)smem;
    u16* Bks = (u16*)(smem + 8192);
    u16* Bvs = (u16*)(smem + 16384);
    u16 (*LTo)[72] = (u16(*)[72])smem;

    const int t = threadIdx.x;
    const int m0 = blockIdx.x * 64, n0 = blockIdx.y * 64;
    const int lane = t & 63, wid = t >> 6;
    const int i16 = lane & 15, g = lane >> 4;
    const int wm = wid >> 1, wn = wid & 1;
    const int row_a = t >> 3, c8 = t & 7;

    f32x4 ak[2][2] = {{{0.f,0.f,0.f,0.f},{0.f,0.f,0.f,0.f}},
                      {{0.f,0.f,0.f,0.f},{0.f,0.f,0.f,0.f}}};
    f32x4 av[2][2] = {{{0.f,0.f,0.f,0.f},{0.f,0.f,0.f,0.f}},
                      {{0.f,0.f,0.f,0.f},{0.f,0.f,0.f,0.f}}};
    const float bk0 = bk[n0 + wn * 32 + i16];
    const float bk1 = bk[n0 + wn * 32 + 16 + i16];
    const float bv0 = bv[n0 + wn * 32 + i16];
    const float bv1 = bv[n0 + wn * 32 + 16 + i16];

    for (int c0 = 0; c0 < C_; c0 += 64) {
        __syncthreads();
        #pragma unroll
        for (int r = 0; r < 2; ++r) {
            const int m = row_a + r * 32;
            const int sw = m * 64 + ((c8 ^ (m & 7)) << 3);
            *(short8_t*)&As[sw]  = *(const short8_t*)&A[(size_t)(m0 + m) * C_ + c0 + c8 * 8];
            *(short8_t*)&Bks[sw] = *(const short8_t*)&Wkb[(size_t)(n0 + m) * C_ + c0 + c8 * 8];
            *(short8_t*)&Bvs[sw] = *(const short8_t*)&Wvb[(size_t)(n0 + m) * C_ + c0 + c8 * 8];
        }
        __syncthreads();
        #pragma unroll
        for (int ks = 0; ks < 2; ++ks) {
            short8_t a[2], bbk[2], bbv[2];
            #pragma unroll
            for (int mt = 0; mt < 2; ++mt) {
                const int m = wm * 32 + mt * 16 + i16;
                a[mt] = *(const short8_t*)&As[m * 64 + ((((ks << 2) | g) ^ (m & 7)) << 3)];
            }
            #pragma unroll
            for (int nt = 0; nt < 2; ++nt) {
                const int d = wn * 32 + nt * 16 + i16;
                const int sw = d * 64 + ((((ks << 2) | g) ^ (d & 7)) << 3);
                bbk[nt] = *(const short8_t*)&Bks[sw];
                bbv[nt] = *(const short8_t*)&Bvs[sw];
            }
            #pragma unroll
            for (int mt = 0; mt < 2; ++mt)
                #pragma unroll
                for (int nt = 0; nt < 2; ++nt) {
                    ak[mt][nt] = __builtin_amdgcn_mfma_f32_16x16x32_bf16(
                        a[mt], bbk[nt], ak[mt][nt], 0, 0, 0);
                    av[mt][nt] = __builtin_amdgcn_mfma_f32_16x16x32_bf16(
                        a[mt], bbv[nt], av[mt][nt], 0, 0, 0);
                }
        }
    }
    // V direct transposed stores: lane col d fixed, 4 consecutive l per frag
    const int nb = m0 >> 8, l0 = m0 & 255;
    const size_t vtbase = (size_t)nb * C_ * L_;
    #pragma unroll
    for (int mt = 0; mt < 2; ++mt)
        #pragma unroll
        for (int nt = 0; nt < 2; ++nt) {
            const int d = n0 + wn * 32 + nt * 16 + i16;
            const float bb = nt ? bv1 : bv0;
            ushort4 w;
            w.x = f2bs(av[mt][nt][0] + bb);
            w.y = f2bs(av[mt][nt][1] + bb);
            w.z = f2bs(av[mt][nt][2] + bb);
            w.w = f2bs(av[mt][nt][3] + bb);
            const int l = l0 + wm * 32 + mt * 16 + g * 4;
            *(ushort4*)&Vt[vtbase + (size_t)d * L_ + l] = w;
        }
    // K through LDS bounce
    __syncthreads();
    #pragma unroll
    for (int mt = 0; mt < 2; ++mt)
        #pragma unroll
        for (int nt = 0; nt < 2; ++nt) {
            const float bb = nt ? bk1 : bk0;
            #pragma unroll
            for (int r = 0; r < 4; ++r)
                LTo[wm * 32 + mt * 16 + g * 4 + r][wn * 32 + nt * 16 + i16] =
                    f2bs(ak[mt][nt][r] + bb);
        }
    __syncthreads();
    #pragma unroll
    for (int rep = 0; rep < 2; ++rep) {
        const int m = (t >> 3) + rep * 32;
        const int cs = (t & 7) * 8;
        *(short8_t*)&Kout[(size_t)(m0 + m) * C_ + n0 + cs] = *(short8_t*)&LTo[m][cs];
    }
}

// ---------------------------------------------------------------------------
// attn (MFMA): unchanged from R1 (verified).
// ---------------------------------------------------------------------------
__global__ __launch_bounds__(256) void attn_kernel(
    const u16* __restrict__ Qws, const u16* __restrict__ Kws,
    const u16* __restrict__ Vws, const float* __restrict__ feature,
    float* __restrict__ out)
{
    __shared__ __align__(16) unsigned char smem[76288];
    u16 (*Qh)[40]   = (u16(*)[40])(smem);
    u16 (*Kh)[40]   = (u16(*)[40])(smem + 5120);
    u16 (*Vt)[264]  = (u16(*)[264])(smem + 25600);
    u16 (*Ph)[264]  = (u16(*)[264])(smem + 42496);
    float (*po)[66] = (float(*)[66])(smem);

    const int t = threadIdx.x;
    const int pt = blockIdx.x;
    const int h  = blockIdx.y;
    const int n  = blockIdx.z;
    const int pos0 = pt * 64;
    const size_t qbase = ((size_t)n * HW_ + pos0) * C_ + h * DH_;
    const size_t kbase = ((size_t)n * L_) * C_ + h * DH_;
    const size_t vbase = (size_t)n * C_ * L_ + (size_t)h * DH_ * L_;

    {
        const int row = t >> 2, ch = t & 3;
        *(short8_t*)&Qh[row][ch * 8] =
            *(const short8_t*)&Qws[qbase + (size_t)row * C_ + ch * 8];
        #pragma unroll
        for (int p = 0; p < 4; ++p) {
            const int r = row + 64 * p;
            *(short8_t*)&Kh[r][ch * 8] =
                *(const short8_t*)&Kws[kbase + (size_t)r * C_ + ch * 8];
        }
        #pragma unroll
        for (int p = 0; p < 4; ++p) {
            const int idx = p * 256 + t;
            const int d = idx >> 5, c = idx & 31;
            *(short8_t*)&Vt[d][c * 8] =
                *(const short8_t*)&Vws[vbase + (size_t)d * L_ + c * 8];
        }
    }
    __syncthreads();

    const int wid = t >> 6, lane = t & 63;
    const int g = lane >> 4, i16 = lane & 15;
    const float inv_scale = 0.17677669529663687f;  // 1/sqrt(32)

    f32x4 s[16];
    {
        short8_t a = *(const short8_t*)&Qh[wid * 16 + i16][g * 8];
        #pragma unroll
        for (int nf = 0; nf < 16; ++nf) {
            short8_t b = *(const short8_t*)&Kh[nf * 16 + i16][g * 8];
            f32x4 z = {0.f, 0.f, 0.f, 0.f};
            s[nf] = __builtin_amdgcn_mfma_f32_16x16x32_bf16(a, b, z, 0, 0, 0);
        }
    }

    float mx[4], inv[4];
    #pragma unroll
    for (int r = 0; r < 4; ++r) {
        float m = s[0][r];
        #pragma unroll
        for (int nf = 1; nf < 16; ++nf) m = fmaxf(m, s[nf][r]);
        #pragma unroll
        for (int off = 8; off >= 1; off >>= 1) m = fmaxf(m, __shfl_xor(m, off));
        mx[r] = m;
    }
    #pragma unroll
    for (int r = 0; r < 4; ++r) {
        float ss = 0.f;
        #pragma unroll
        for (int nf = 0; nf < 16; ++nf) {
            float e = __expf((s[nf][r] - mx[r]) * inv_scale);
            s[nf][r] = e;
            ss += e;
        }
        #pragma unroll
        for (int off = 8; off >= 1; off >>= 1) ss += __shfl_xor(ss, off);
        inv[r] = 1.0f / ss;
    }
    #pragma unroll
    for (int r = 0; r < 4; ++r) {
        const int q = wid * 16 + g * 4 + r;
        #pragma unroll
        for (int nf = 0; nf < 16; ++nf)
            Ph[q][nf * 16 + i16] = f2bs(s[nf][r] * inv[r]);
    }
    __syncthreads();

    f32x4 o0 = {0.f, 0.f, 0.f, 0.f}, o1 = {0.f, 0.f, 0.f, 0.f};
    #pragma unroll
    for (int ks = 0; ks < 8; ++ks) {
        short8_t pa  = *(const short8_t*)&Ph[wid * 16 + i16][ks * 32 + g * 8];
        short8_t vb0 = *(const short8_t*)&Vt[i16][ks * 32 + g * 8];
        short8_t vb1 = *(const short8_t*)&Vt[16 + i16][ks * 32 + g * 8];
        o0 = __builtin_amdgcn_mfma_f32_16x16x32_bf16(pa, vb0, o0, 0, 0, 0);
        o1 = __builtin_amdgcn_mfma_f32_16x16x32_bf16(pa, vb1, o1, 0, 0, 0);
    }
    #pragma unroll
    for (int r = 0; r < 4; ++r) {
        const int q = wid * 16 + g * 4 + r;
        po[i16][q]      = o0[r];
        po[16 + i16][q] = o1[r];
    }
    __syncthreads();

    #pragma unroll
    for (int p = 0; p < 8; ++p) {
        const int e = p * 256 + t;
        const int d = e >> 6, q = e & 63;
        const size_t o = ((size_t)n * C_ + h * DH_ + d) * HW_ + pos0 + q;
        out[o] = feature[o] + po[d][q];
    }
}

extern "C" void kernel_launch(void* const* d_in, const int* in_sizes, int n_in,
                              void* d_out, int out_size, void* d_ws, size_t ws_size,
                              hipStream_t stream)
{
    const float* feature = (const float*)d_in[0];
    const float* token   = (const float*)d_in[1];
    const float* wq      = (const float*)d_in[2];
    const float* bq      = (const float*)d_in[3];
    const float* wk      = (const float*)d_in[4];
    const float* bk      = (const float*)d_in[5];
    const float* wv      = (const float*)d_in[6];
    const float* bv      = (const float*)d_in[7];
    float* out = (float*)d_out;

    // ws: Q [16384][512] bf16 (16 MiB) | K [4096][512] (4 MiB) | Vt [n][d][l] (4 MiB)
    u16* Qws = (u16*)d_ws;
    u16* Kws = Qws + (size_t)N_ * HW_ * C_;
    u16* Vws = Kws + (size_t)N_ * L_ * C_;

    // d_out doubles as scratch before attn overwrites it (32 MiB):
    //   [0,16M): Ft bf16 | [16M,20M): token bf16 | [20M,21.5M): wq/wk/wv bf16
    char* ob = (char*)d_out;
    u16* Ft   = (u16*)ob;
    u16* tokb = (u16*)(ob + (16u << 20));
    u16* wqb  = (u16*)(ob + (20u << 20));
    u16* wkb  = (u16*)(ob + (20u << 20) + 524288);
    u16* wvb  = (u16*)(ob + (20u << 20) + 1048576);

    prep_kernel<<<dim3(2816), 256, 0, stream>>>(token, wq, wk, wv,
                                                tokb, wqb, wkb, wvb);
    transpose_f_kernel<<<dim3(16, 8, 16), 256, 0, stream>>>(feature, Ft);
    gemm_q_kernel<<<dim3(256, 8), 256, 0, stream>>>(Ft, wqb, bq, Qws);
    gemm_kv_kernel<<<dim3(64, 8), 256, 0, stream>>>(tokb, wkb, wvb, bk, bv,
                                                    Kws, Vws);
    attn_kernel<<<dim3(16, 16, 16), 256, 0, stream>>>(Qws, Kws, Vws, feature, out);
}

// Round 4
// 80.559 us; speedup vs baseline: 7.3178x; 1.1122x over previous
//
#include <hip/hip_runtime.h>
#include <hip/hip_bf16.h>

#define N_ 16
#define L_ 256
#define C_ 512
#define HW_ 1024
#define HEADS_ 16
#define DH_ 32

typedef unsigned short u16;
typedef unsigned int u32;
typedef __attribute__((ext_vector_type(8))) short short8_t;
typedef __attribute__((ext_vector_type(4))) float f32x4;

__device__ __forceinline__ u16 f2bs(float f) {
    union { float f; u32 i; } x; x.f = f;
    u32 r = x.i + 0x7fffu + ((x.i >> 16) & 1u);
    return (u16)(r >> 16);
}
__device__ __forceinline__ u32 cvt_pk_bf16(float lo, float hi) {
    u32 r;
    asm("v_cvt_pk_bf16_f32 %0, %1, %2" : "=v"(r) : "v"(lo), "v"(hi));
    return r;
}

// ---------------------------------------------------------------------------
// prep: flat fp32->bf16 converts: token (524288 f4), wq/wk/wv (65536 f4 each).
// ---------------------------------------------------------------------------
__global__ __launch_bounds__(256) void prep_kernel(
    const float* __restrict__ token, const float* __restrict__ wq,
    const float* __restrict__ wk, const float* __restrict__ wv,
    u16* __restrict__ tokb, u16* __restrict__ wqb,
    u16* __restrict__ wkb, u16* __restrict__ wvb)
{
    const int idx = blockIdx.x * 256 + threadIdx.x;
    const float* s; u16* d; int off;
    if (idx < 524288)            { s = token; d = tokb; off = idx; }
    else if (idx < 524288+65536) { s = wq; d = wqb; off = idx - 524288; }
    else if (idx < 524288+131072){ s = wk; d = wkb; off = idx - 524288 - 65536; }
    else                         { s = wv; d = wvb; off = idx - 524288 - 131072; }
    float4 v = ((const float4*)s)[off];
    ushort4 w;
    w.x = f2bs(v.x); w.y = f2bs(v.y); w.z = f2bs(v.z); w.w = f2bs(v.w);
    ((ushort4*)d)[off] = w;
}

// ---------------------------------------------------------------------------
// transpose_f: feature [n][c][pos] f32 -> Ft [(n*HW+pos)][c] bf16.
// ---------------------------------------------------------------------------
__global__ __launch_bounds__(256) void transpose_f_kernel(
    const float* __restrict__ feature, u16* __restrict__ Ft)
{
    __shared__ float LT[64][67];
    const int t = threadIdx.x;
    const int pb = blockIdx.x, cb = blockIdx.y, n = blockIdx.z;
    const int c0 = cb * 64, pos0 = pb * 64;

    #pragma unroll
    for (int r = 0; r < 4; ++r) {
        const int c = r * 16 + (t >> 4);
        const int p = (t & 15) * 4;
        float4 v = *(const float4*)&feature[((size_t)n * C_ + c0 + c) * HW_ + pos0 + p];
        LT[c][p] = v.x; LT[c][p+1] = v.y; LT[c][p+2] = v.z; LT[c][p+3] = v.w;
    }
    __syncthreads();
    #pragma unroll
    for (int rep = 0; rep < 2; ++rep) {
        const int pos = (t >> 3) + rep * 32;
        const int c = (t & 7) * 8;
        u16 tmp[8];
        #pragma unroll
        for (int j = 0; j < 8; ++j) tmp[j] = f2bs(LT[c + j][pos]);
        *(short8_t*)&Ft[(size_t)(n * HW_ + pos0 + pos) * C_ + c0 + c] =
            *(short8_t*)tmp;
    }
}

// ---------------------------------------------------------------------------
// gemm_q (MFMA): Out[m][dout] = sum_c A[m][c]*W[dout][c] + bias[dout].
// ---------------------------------------------------------------------------
__global__ __launch_bounds__(256) void gemm_q_kernel(
    const u16* __restrict__ A, const u16* __restrict__ Wb,
    const float* __restrict__ bias, u16* __restrict__ Out)
{
    __shared__ __align__(16) unsigned char smem[16384];
    u16* As = (u16*)smem;
    u16* Bs = (u16*)(smem + 8192);
    u16 (*LTo)[72] = (u16(*)[72])smem;

    const int t = threadIdx.x;
    const int m0 = blockIdx.x * 64, n0 = blockIdx.y * 64;
    const int lane = t & 63, wid = t >> 6;
    const int i16 = lane & 15, g = lane >> 4;
    const int wm = wid >> 1, wn = wid & 1;
    const int row_a = t >> 3, c8 = t & 7;

    f32x4 acc[2][2] = {{{0.f,0.f,0.f,0.f},{0.f,0.f,0.f,0.f}},
                       {{0.f,0.f,0.f,0.f},{0.f,0.f,0.f,0.f}}};
    const float b0 = bias[n0 + wn * 32 + i16];
    const float b1 = bias[n0 + wn * 32 + 16 + i16];

    for (int c0 = 0; c0 < C_; c0 += 64) {
        __syncthreads();
        #pragma unroll
        for (int r = 0; r < 2; ++r) {
            const int m = row_a + r * 32;
            short8_t va = *(const short8_t*)&A[(size_t)(m0 + m) * C_ + c0 + c8 * 8];
            *(short8_t*)&As[m * 64 + ((c8 ^ (m & 7)) << 3)] = va;
            short8_t vb = *(const short8_t*)&Wb[(size_t)(n0 + m) * C_ + c0 + c8 * 8];
            *(short8_t*)&Bs[m * 64 + ((c8 ^ (m & 7)) << 3)] = vb;
        }
        __syncthreads();
        #pragma unroll
        for (int ks = 0; ks < 2; ++ks) {
            short8_t a[2], b[2];
            #pragma unroll
            for (int mt = 0; mt < 2; ++mt) {
                const int m = wm * 32 + mt * 16 + i16;
                a[mt] = *(const short8_t*)&As[m * 64 + ((((ks << 2) | g) ^ (m & 7)) << 3)];
            }
            #pragma unroll
            for (int nt = 0; nt < 2; ++nt) {
                const int d = wn * 32 + nt * 16 + i16;
                b[nt] = *(const short8_t*)&Bs[d * 64 + ((((ks << 2) | g) ^ (d & 7)) << 3)];
            }
            #pragma unroll
            for (int mt = 0; mt < 2; ++mt)
                #pragma unroll
                for (int nt = 0; nt < 2; ++nt)
                    acc[mt][nt] = __builtin_amdgcn_mfma_f32_16x16x32_bf16(
                        a[mt], b[nt], acc[mt][nt], 0, 0, 0);
        }
    }
    __syncthreads();
    #pragma unroll
    for (int mt = 0; mt < 2; ++mt)
        #pragma unroll
        for (int nt = 0; nt < 2; ++nt) {
            const float bb = nt ? b1 : b0;
            #pragma unroll
            for (int r = 0; r < 4; ++r)
                LTo[wm * 32 + mt * 16 + g * 4 + r][wn * 32 + nt * 16 + i16] =
                    f2bs(acc[mt][nt][r] + bb);
        }
    __syncthreads();
    #pragma unroll
    for (int rep = 0; rep < 2; ++rep) {
        const int m = (t >> 3) + rep * 32;
        const int cs = (t & 7) * 8;
        *(short8_t*)&Out[(size_t)(m0 + m) * C_ + n0 + cs] = *(short8_t*)&LTo[m][cs];
    }
}

// ---------------------------------------------------------------------------
// gemm_kv (MFMA): K row-major out (LDS bounce), V transposed out [nb][dout][l].
// ---------------------------------------------------------------------------
__global__ __launch_bounds__(256) void gemm_kv_kernel(
    const u16* __restrict__ A, const u16* __restrict__ Wkb,
    const u16* __restrict__ Wvb, const float* __restrict__ bk,
    const float* __restrict__ bv, u16* __restrict__ Kout, u16* __restrict__ Vt)
{
    __shared__ __align__(16) unsigned char smem[24576];
    u16* As  = (u16*)smem;
    u16* Bks = (u16*)(smem + 8192);
    u16* Bvs = (u16*)(smem + 16384);
    u16 (*LTo)[72] = (u16(*)[72])smem;

    const int t = threadIdx.x;
    const int m0 = blockIdx.x * 64, n0 = blockIdx.y * 64;
    const int lane = t & 63, wid = t >> 6;
    const int i16 = lane & 15, g = lane >> 4;
    const int wm = wid >> 1, wn = wid & 1;
    const int row_a = t >> 3, c8 = t & 7;

    f32x4 ak[2][2] = {{{0.f,0.f,0.f,0.f},{0.f,0.f,0.f,0.f}},
                      {{0.f,0.f,0.f,0.f},{0.f,0.f,0.f,0.f}}};
    f32x4 av[2][2] = {{{0.f,0.f,0.f,0.f},{0.f,0.f,0.f,0.f}},
                      {{0.f,0.f,0.f,0.f},{0.f,0.f,0.f,0.f}}};
    const float bk0 = bk[n0 + wn * 32 + i16];
    const float bk1 = bk[n0 + wn * 32 + 16 + i16];
    const float bv0 = bv[n0 + wn * 32 + i16];
    const float bv1 = bv[n0 + wn * 32 + 16 + i16];

    for (int c0 = 0; c0 < C_; c0 += 64) {
        __syncthreads();
        #pragma unroll
        for (int r = 0; r < 2; ++r) {
            const int m = row_a + r * 32;
            const int sw = m * 64 + ((c8 ^ (m & 7)) << 3);
            *(short8_t*)&As[sw]  = *(const short8_t*)&A[(size_t)(m0 + m) * C_ + c0 + c8 * 8];
            *(short8_t*)&Bks[sw] = *(const short8_t*)&Wkb[(size_t)(n0 + m) * C_ + c0 + c8 * 8];
            *(short8_t*)&Bvs[sw] = *(const short8_t*)&Wvb[(size_t)(n0 + m) * C_ + c0 + c8 * 8];
        }
        __syncthreads();
        #pragma unroll
        for (int ks = 0; ks < 2; ++ks) {
            short8_t a[2], bbk[2], bbv[2];
            #pragma unroll
            for (int mt = 0; mt < 2; ++mt) {
                const int m = wm * 32 + mt * 16 + i16;
                a[mt] = *(const short8_t*)&As[m * 64 + ((((ks << 2) | g) ^ (m & 7)) << 3)];
            }
            #pragma unroll
            for (int nt = 0; nt < 2; ++nt) {
                const int d = wn * 32 + nt * 16 + i16;
                const int sw = d * 64 + ((((ks << 2) | g) ^ (d & 7)) << 3);
                bbk[nt] = *(const short8_t*)&Bks[sw];
                bbv[nt] = *(const short8_t*)&Bvs[sw];
            }
            #pragma unroll
            for (int mt = 0; mt < 2; ++mt)
                #pragma unroll
                for (int nt = 0; nt < 2; ++nt) {
                    ak[mt][nt] = __builtin_amdgcn_mfma_f32_16x16x32_bf16(
                        a[mt], bbk[nt], ak[mt][nt], 0, 0, 0);
                    av[mt][nt] = __builtin_amdgcn_mfma_f32_16x16x32_bf16(
                        a[mt], bbv[nt], av[mt][nt], 0, 0, 0);
                }
        }
    }
    const int nb = m0 >> 8, l0 = m0 & 255;
    const size_t vtbase = (size_t)nb * C_ * L_;
    #pragma unroll
    for (int mt = 0; mt < 2; ++mt)
        #pragma unroll
        for (int nt = 0; nt < 2; ++nt) {
            const int d = n0 + wn * 32 + nt * 16 + i16;
            const float bb = nt ? bv1 : bv0;
            ushort4 w;
            w.x = f2bs(av[mt][nt][0] + bb);
            w.y = f2bs(av[mt][nt][1] + bb);
            w.z = f2bs(av[mt][nt][2] + bb);
            w.w = f2bs(av[mt][nt][3] + bb);
            const int l = l0 + wm * 32 + mt * 16 + g * 4;
            *(ushort4*)&Vt[vtbase + (size_t)d * L_ + l] = w;
        }
    __syncthreads();
    #pragma unroll
    for (int mt = 0; mt < 2; ++mt)
        #pragma unroll
        for (int nt = 0; nt < 2; ++nt) {
            const float bb = nt ? bk1 : bk0;
            #pragma unroll
            for (int r = 0; r < 4; ++r)
                LTo[wm * 32 + mt * 16 + g * 4 + r][wn * 32 + nt * 16 + i16] =
                    f2bs(ak[mt][nt][r] + bb);
        }
    __syncthreads();
    #pragma unroll
    for (int rep = 0; rep < 2; ++rep) {
        const int m = (t >> 3) + rep * 32;
        const int cs = (t & 7) * 8;
        *(short8_t*)&Kout[(size_t)(m0 + m) * C_ + n0 + cs] = *(short8_t*)&LTo[m][cs];
    }
}

// ---------------------------------------------------------------------------
// attn v2 (swapped-QK MFMA): block = (64 pos, head, batch), 4 waves; each
// wave owns q = wid*16 + i16 (lane-fixed q, full P-row per lane).
//  - K [256][32] u16 LINEAR at smem[0,16K), staged via global_load_lds w=16.
//  - V^T [32][256] u16 granule-XOR-swizzled at smem[16K,32K) (pre-swizzled
//    global source, linear LDS dest -> rule 21 satisfied).
//  - QK^T: s[nf] = mfma(K-rows, Qfrag) -> lane holds P-row (64 of 256 l).
//  - softmax: in-lane tree + shfl_xor(16,32); exp2 with folded 1/sqrt(d).
//  - P packed to bf16 pairs (v_cvt_pk_bf16_f32) -> half-buffer Ph [64][128]
//    XOR-swizzled, ALIASES dead Kh; two write->PV rounds (ks 0..3, 4..7).
//  - PV: o = mfma(Vt-rows(d), P-rows(q)) -> lane: col=q, rows=d -> direct
//    coalesced epilogue out = feature + o (64B segments), no LDS bounce.
// LDS total 32 KB -> 5 blocks/CU (VGPR permitting ~4).
// ---------------------------------------------------------------------------
__global__ __launch_bounds__(256) void attn_kernel(
    const u16* __restrict__ Qws, const u16* __restrict__ Kws,
    const u16* __restrict__ Vws, const float* __restrict__ feature,
    float* __restrict__ out)
{
    __shared__ __align__(16) unsigned char smem[32768];

    const int t = threadIdx.x;
    const int wid = t >> 6, lane = t & 63;
    const int i16 = lane & 15, g = lane >> 4;
    const int pt = blockIdx.x, h = blockIdx.y, n = blockIdx.z;
    const int pos0 = pt * 64;
    const size_t qbase = ((size_t)n * HW_ + pos0) * C_ + h * DH_;
    const size_t kbase = ((size_t)n * L_) * C_ + h * DH_;
    const size_t vbase = (size_t)n * C_ * L_ + (size_t)h * DH_ * L_;

    const int q = wid * 16 + i16;

    // Q b-frag: one 16B global load per lane
    short8_t bq = *(const short8_t*)&Qws[qbase + (size_t)q * C_ + g * 8];

    // stage K (linear) + V^T (swizzled source) via global_load_lds
    #pragma unroll
    for (int p = 0; p < 4; ++p) {
        const int kr = wid * 64 + p * 16 + (lane >> 2);
        const u16* ksrc = Kws + kbase + (size_t)kr * C_ + (lane & 3) * 8;
        __builtin_amdgcn_global_load_lds(
            (const __attribute__((address_space(1))) void*)ksrc,
            (__attribute__((address_space(3))) void*)(smem + wid * 4096 + p * 1024),
            16, 0, 0);
        const int vd = wid * 8 + p * 2 + (lane >> 5);
        const u16* vsrc = Vws + vbase + (size_t)vd * L_ + ((lane & 31) ^ (vd & 7)) * 8;
        __builtin_amdgcn_global_load_lds(
            (const __attribute__((address_space(1))) void*)vsrc,
            (__attribute__((address_space(3))) void*)(smem + 16384 + wid * 4096 + p * 1024),
            16, 0, 0);
    }
    __syncthreads();

    // QK^T swapped: s[nf] rows = l = nf*16 + g*4 + r, col = q (lane i16)
    f32x4 s[16];
    #pragma unroll
    for (int nf = 0; nf < 16; ++nf) {
        short8_t a = *(const short8_t*)(smem + (nf * 16 + i16) * 64 + g * 16);
        f32x4 z = {0.f, 0.f, 0.f, 0.f};
        s[nf] = __builtin_amdgcn_mfma_f32_16x16x32_bf16(a, bq, z, 0, 0, 0);
    }

    // softmax over l for fixed q: in-lane tree + cross-g shuffles
    float mm[16], sm[16];
    #pragma unroll
    for (int nf = 0; nf < 16; ++nf)
        mm[nf] = fmaxf(fmaxf(s[nf][0], s[nf][1]), fmaxf(s[nf][2], s[nf][3]));
    #pragma unroll
    for (int st = 8; st >= 1; st >>= 1)
        #pragma unroll
        for (int i = 0; i < 8; ++i)
            if (i < st) mm[i] = fmaxf(mm[i], mm[i + st]);
    float m = mm[0];
    m = fmaxf(m, __shfl_xor(m, 16));
    m = fmaxf(m, __shfl_xor(m, 32));

    const float K2 = 0.25506288f;  // log2(e) / sqrt(32)
    #pragma unroll
    for (int nf = 0; nf < 16; ++nf) {
        #pragma unroll
        for (int r = 0; r < 4; ++r) s[nf][r] = exp2f((s[nf][r] - m) * K2);
        sm[nf] = (s[nf][0] + s[nf][1]) + (s[nf][2] + s[nf][3]);
    }
    #pragma unroll
    for (int st = 8; st >= 1; st >>= 1)
        #pragma unroll
        for (int i = 0; i < 8; ++i)
            if (i < st) sm[i] += sm[i + st];
    float ssum = sm[0];
    ssum += __shfl_xor(ssum, 16);
    ssum += __shfl_xor(ssum, 32);
    const float pinv = 1.0f / ssum;

    __syncthreads();  // Kh dead -> Ph may alias

    f32x4 o0 = {0.f, 0.f, 0.f, 0.f}, o1 = {0.f, 0.f, 0.f, 0.f};
    const int e7 = i16 & 7;

    #pragma unroll
    for (int hb = 0; hb < 2; ++hb) {
        // write P half: pairs (l even) packed via v_cvt_pk_bf16_f32
        #pragma unroll
        for (int nfp = 0; nfp < 8; ++nfp) {
            const int nf = hb * 8 + nfp;
            #pragma unroll
            for (int w = 0; w < 2; ++w) {
                u32 pw = cvt_pk_bf16(s[nf][2 * w] * pinv, s[nf][2 * w + 1] * pinv);
                const int gran = (nfp * 2 + (g >> 1)) ^ e7;
                *(u32*)(smem + q * 256 + gran * 16 + ((g & 1) * 2 + w) * 4) = pw;
            }
        }
        __syncthreads();
        // PV quarter-chunks ks (l = (hb*4+ks)*32 + g*8 ..)
        #pragma unroll
        for (int ks = 0; ks < 4; ++ks) {
            short8_t pb = *(const short8_t*)(smem + q * 256 + (((ks * 4 + g) ^ e7) * 16));
            const int vg = (((hb * 4 + ks) * 4 + g) ^ e7) * 16;
            short8_t va0 = *(const short8_t*)(smem + 16384 + i16 * 512 + vg);
            short8_t va1 = *(const short8_t*)(smem + 16384 + (16 + i16) * 512 + vg);
            o0 = __builtin_amdgcn_mfma_f32_16x16x32_bf16(va0, pb, o0, 0, 0, 0);
            o1 = __builtin_amdgcn_mfma_f32_16x16x32_bf16(va1, pb, o1, 0, 0, 0);
        }
        if (hb == 0) __syncthreads();
    }

    // epilogue: lane col=q, rows d = g*4+r (+16); coalesced 64B segments
    const size_t obase = ((size_t)n * C_ + h * DH_) * HW_ + pos0 + q;
    #pragma unroll
    for (int r = 0; r < 4; ++r) {
        const size_t oa = obase + (size_t)(g * 4 + r) * HW_;
        out[oa] = feature[oa] + o0[r];
        const size_t ob = obase + (size_t)(16 + g * 4 + r) * HW_;
        out[ob] = feature[ob] + o1[r];
    }
}

extern "C" void kernel_launch(void* const* d_in, const int* in_sizes, int n_in,
                              void* d_out, int out_size, void* d_ws, size_t ws_size,
                              hipStream_t stream)
{
    const float* feature = (const float*)d_in[0];
    const float* token   = (const float*)d_in[1];
    const float* wq      = (const float*)d_in[2];
    const float* bq      = (const float*)d_in[3];
    const float* wk      = (const float*)d_in[4];
    const float* bk      = (const float*)d_in[5];
    const float* wv      = (const float*)d_in[6];
    const float* bv      = (const float*)d_in[7];
    float* out = (float*)d_out;

    // ws: Q [16384][512] bf16 (16 MiB) | K [4096][512] (4 MiB) | Vt [n][d][l] (4 MiB)
    u16* Qws = (u16*)d_ws;
    u16* Kws = Qws + (size_t)N_ * HW_ * C_;
    u16* Vws = Kws + (size_t)N_ * L_ * C_;

    // d_out doubles as scratch before attn overwrites it (32 MiB)
    char* ob = (char*)d_out;
    u16* Ft   = (u16*)ob;
    u16* tokb = (u16*)(ob + (16u << 20));
    u16* wqb  = (u16*)(ob + (20u << 20));
    u16* wkb  = (u16*)(ob + (20u << 20) + 524288);
    u16* wvb  = (u16*)(ob + (20u << 20) + 1048576);

    prep_kernel<<<dim3(2816), 256, 0, stream>>>(token, wq, wk, wv,
                                                tokb, wqb, wkb, wvb);
    transpose_f_kernel<<<dim3(16, 8, 16), 256, 0, stream>>>(feature, Ft);
    gemm_q_kernel<<<dim3(256, 8), 256, 0, stream>>>(Ft, wqb, bq, Qws);
    gemm_kv_kernel<<<dim3(64, 8), 256, 0, stream>>>(tokb, wkb, wvb, bk, bv,
                                                    Kws, Vws);
    attn_kernel<<<dim3(16, 16, 16), 256, 0, stream>>>(Qws, Kws, Vws, feature, out);
}

// Round 5
// 78.965 us; speedup vs baseline: 7.4656x; 1.0202x over previous
//
#include <hip/hip_runtime.h>
#include <hip/hip_bf16.h>

#define N_ 16
#define L_ 256
#define C_ 512
#define HW_ 1024
#define HEADS_ 16
#define DH_ 32

typedef unsigned short u16;
typedef unsigned int u32;
typedef __attribute__((ext_vector_type(8))) short short8_t;
typedef __attribute__((ext_vector_type(4))) float f32x4;
typedef __attribute__((ext_vector_type(2))) unsigned int u32x2;

__device__ __forceinline__ u16 f2bs(float f) {
    union { float f; u32 i; } x; x.f = f;
    u32 r = x.i + 0x7fffu + ((x.i >> 16) & 1u);
    return (u16)(r >> 16);
}
__device__ __forceinline__ u32 cvt_pk_bf16(float lo, float hi) {
    u32 r;
    asm("v_cvt_pk_bf16_f32 %0, %1, %2" : "=v"(r) : "v"(lo), "v"(hi));
    return r;
}

// ---------------------------------------------------------------------------
// prep: flat fp32->bf16 converts: token (524288 f4), wq/wk/wv (65536 f4 each).
// ---------------------------------------------------------------------------
__global__ __launch_bounds__(256) void prep_kernel(
    const float* __restrict__ token, const float* __restrict__ wq,
    const float* __restrict__ wk, const float* __restrict__ wv,
    u16* __restrict__ tokb, u16* __restrict__ wqb,
    u16* __restrict__ wkb, u16* __restrict__ wvb)
{
    const int idx = blockIdx.x * 256 + threadIdx.x;
    const float* s; u16* d; int off;
    if (idx < 524288)            { s = token; d = tokb; off = idx; }
    else if (idx < 524288+65536) { s = wq; d = wqb; off = idx - 524288; }
    else if (idx < 524288+131072){ s = wk; d = wkb; off = idx - 524288 - 65536; }
    else                         { s = wv; d = wvb; off = idx - 524288 - 131072; }
    float4 v = ((const float4*)s)[off];
    ushort4 w;
    w.x = f2bs(v.x); w.y = f2bs(v.y); w.z = f2bs(v.z); w.w = f2bs(v.w);
    ((ushort4*)d)[off] = w;
}

// ---------------------------------------------------------------------------
// gemm_qf (MFMA, fused feature-transpose): Q[m=pos][d] = sum_c
// feature[n][c][pos]*Wq[d][c] + bq[d].  A = Wq (granule-swizzled LDS rows),
// B = feature staged [cb][pb][4][16] subtiled; B-frags via ds_read_b64_tr_b16
// (elem j = lds_u16[vaddr/2 + j*16] per lane -> 4 consecutive c per read,
// 2 reads = K=32 frag half for group g). D: row=d, col=pos -> direct
// coalesced ushort4 stores (4 consecutive d per lane), no LDS bounce.
// ---------------------------------------------------------------------------
__global__ __launch_bounds__(256) void gemm_qf_kernel(
    const float* __restrict__ feature, const u16* __restrict__ Wb,
    const float* __restrict__ bias, u16* __restrict__ Out)
{
    __shared__ __align__(16) unsigned char smem[16384];
    u16* As = (u16*)smem;            // Wq tile [64][64] granule-swizzled
    u16* Bs = (u16*)(smem + 8192);   // feature subtiled [16 cb][4 pb][4][16]

    const int t = threadIdx.x;
    const int m0 = blockIdx.x * 64, n0 = blockIdx.y * 64;
    const int n = m0 >> 10, pos0 = m0 & (HW_ - 1);
    const int lane = t & 63, wid = t >> 6;
    const int i16 = lane & 15, g = lane >> 4;
    const int wm = wid >> 1, wn = wid & 1;
    const int row_a = t >> 3, c8 = t & 7;
    const int cst = t >> 2, pq = t & 3;   // feature staging: c row, pos quad

    f32x4 acc[2][2] = {{{0.f,0.f,0.f,0.f},{0.f,0.f,0.f,0.f}},
                       {{0.f,0.f,0.f,0.f},{0.f,0.f,0.f,0.f}}};

    for (int c0 = 0; c0 < C_; c0 += 64) {
        __syncthreads();
        // stage Wq rows (granule-XOR swizzle)
        #pragma unroll
        for (int r = 0; r < 2; ++r) {
            const int m = row_a + r * 32;
            *(short8_t*)&As[m * 64 + ((c8 ^ (m & 7)) << 3)] =
                *(const short8_t*)&Wb[(size_t)(n0 + m) * C_ + c0 + c8 * 8];
        }
        // stage feature tile [64 c][64 pos] -> subtiled bf16
        #pragma unroll
        for (int j = 0; j < 4; ++j) {
            const int pos = j * 16 + pq * 4;
            float4 v = *(const float4*)&feature[
                ((size_t)n * C_ + c0 + cst) * HW_ + pos0 + pos];
            ushort4 w;
            w.x = f2bs(v.x); w.y = f2bs(v.y); w.z = f2bs(v.z); w.w = f2bs(v.w);
            *(ushort4*)&Bs[(cst >> 2) * 256 + j * 64 + (cst & 3) * 16 + pq * 4] = w;
        }
        __syncthreads();
        #pragma unroll
        for (int ks = 0; ks < 2; ++ks) {
            short8_t a[2];
            #pragma unroll
            for (int mt = 0; mt < 2; ++mt) {
                const int m = wm * 32 + mt * 16 + i16;
                a[mt] = *(const short8_t*)&As[m * 64 + ((((ks << 2) | g) ^ (m & 7)) << 3)];
            }
            short8_t b[2];
            #pragma unroll
            for (int nt = 0; nt < 2; ++nt) {
                const int pb = wn * 2 + nt;
                // subtile (cb = ks*8 + g*2, pb), column i16
                const u32 vaddr = 8192 +
                    (u32)(ks * 32 + g * 8 + pb) * 128 + (u32)i16 * 2;
                u32x2 lo, hi;
                asm volatile("ds_read_b64_tr_b16 %0, %1"
                             : "=v"(lo) : "v"(vaddr));
                asm volatile("ds_read_b64_tr_b16 %0, %1 offset:512"
                             : "=v"(hi) : "v"(vaddr));
                union { u32 w[4]; short8_t v; } pk;
                pk.w[0] = lo[0]; pk.w[1] = lo[1];
                pk.w[2] = hi[0]; pk.w[3] = hi[1];
                b[nt] = pk.v;
            }
            asm volatile("s_waitcnt lgkmcnt(0)" ::: "memory");
            __builtin_amdgcn_sched_barrier(0);
            #pragma unroll
            for (int mt = 0; mt < 2; ++mt)
                #pragma unroll
                for (int nt = 0; nt < 2; ++nt)
                    acc[mt][nt] = __builtin_amdgcn_mfma_f32_16x16x32_bf16(
                        a[mt], b[nt], acc[mt][nt], 0, 0, 0);
        }
    }
    // epilogue: lane holds 4 consecutive d (rows) for col pos
    #pragma unroll
    for (int mt = 0; mt < 2; ++mt) {
        const int dbase = wm * 32 + mt * 16 + g * 4;
        float4 b4 = *(const float4*)&bias[n0 + dbase];
        const float bb[4] = {b4.x, b4.y, b4.z, b4.w};
        #pragma unroll
        for (int nt = 0; nt < 2; ++nt) {
            const int pos = wn * 32 + nt * 16 + i16;
            ushort4 w;
            w.x = f2bs(acc[mt][nt][0] + bb[0]);
            w.y = f2bs(acc[mt][nt][1] + bb[1]);
            w.z = f2bs(acc[mt][nt][2] + bb[2]);
            w.w = f2bs(acc[mt][nt][3] + bb[3]);
            *(ushort4*)&Out[(size_t)(m0 + pos) * C_ + n0 + dbase] = w;
        }
    }
}

// ---------------------------------------------------------------------------
// gemm_kv (MFMA): K row-major out (LDS bounce), V transposed out [nb][dout][l].
// ---------------------------------------------------------------------------
__global__ __launch_bounds__(256) void gemm_kv_kernel(
    const u16* __restrict__ A, const u16* __restrict__ Wkb,
    const u16* __restrict__ Wvb, const float* __restrict__ bk,
    const float* __restrict__ bv, u16* __restrict__ Kout, u16* __restrict__ Vt)
{
    __shared__ __align__(16) unsigned char smem[24576];
    u16* As  = (u16*)smem;
    u16* Bks = (u16*)(smem + 8192);
    u16* Bvs = (u16*)(smem + 16384);
    u16 (*LTo)[72] = (u16(*)[72])smem;

    const int t = threadIdx.x;
    const int m0 = blockIdx.x * 64, n0 = blockIdx.y * 64;
    const int lane = t & 63, wid = t >> 6;
    const int i16 = lane & 15, g = lane >> 4;
    const int wm = wid >> 1, wn = wid & 1;
    const int row_a = t >> 3, c8 = t & 7;

    f32x4 ak[2][2] = {{{0.f,0.f,0.f,0.f},{0.f,0.f,0.f,0.f}},
                      {{0.f,0.f,0.f,0.f},{0.f,0.f,0.f,0.f}}};
    f32x4 av[2][2] = {{{0.f,0.f,0.f,0.f},{0.f,0.f,0.f,0.f}},
                      {{0.f,0.f,0.f,0.f},{0.f,0.f,0.f,0.f}}};
    const float bk0 = bk[n0 + wn * 32 + i16];
    const float bk1 = bk[n0 + wn * 32 + 16 + i16];
    const float bv0 = bv[n0 + wn * 32 + i16];
    const float bv1 = bv[n0 + wn * 32 + 16 + i16];

    for (int c0 = 0; c0 < C_; c0 += 64) {
        __syncthreads();
        #pragma unroll
        for (int r = 0; r < 2; ++r) {
            const int m = row_a + r * 32;
            const int sw = m * 64 + ((c8 ^ (m & 7)) << 3);
            *(short8_t*)&As[sw]  = *(const short8_t*)&A[(size_t)(m0 + m) * C_ + c0 + c8 * 8];
            *(short8_t*)&Bks[sw] = *(const short8_t*)&Wkb[(size_t)(n0 + m) * C_ + c0 + c8 * 8];
            *(short8_t*)&Bvs[sw] = *(const short8_t*)&Wvb[(size_t)(n0 + m) * C_ + c0 + c8 * 8];
        }
        __syncthreads();
        #pragma unroll
        for (int ks = 0; ks < 2; ++ks) {
            short8_t a[2], bbk[2], bbv[2];
            #pragma unroll
            for (int mt = 0; mt < 2; ++mt) {
                const int m = wm * 32 + mt * 16 + i16;
                a[mt] = *(const short8_t*)&As[m * 64 + ((((ks << 2) | g) ^ (m & 7)) << 3)];
            }
            #pragma unroll
            for (int nt = 0; nt < 2; ++nt) {
                const int d = wn * 32 + nt * 16 + i16;
                const int sw = d * 64 + ((((ks << 2) | g) ^ (d & 7)) << 3);
                bbk[nt] = *(const short8_t*)&Bks[sw];
                bbv[nt] = *(const short8_t*)&Bvs[sw];
            }
            #pragma unroll
            for (int mt = 0; mt < 2; ++mt)
                #pragma unroll
                for (int nt = 0; nt < 2; ++nt) {
                    ak[mt][nt] = __builtin_amdgcn_mfma_f32_16x16x32_bf16(
                        a[mt], bbk[nt], ak[mt][nt], 0, 0, 0);
                    av[mt][nt] = __builtin_amdgcn_mfma_f32_16x16x32_bf16(
                        a[mt], bbv[nt], av[mt][nt], 0, 0, 0);
                }
        }
    }
    const int nb = m0 >> 8, l0 = m0 & 255;
    const size_t vtbase = (size_t)nb * C_ * L_;
    #pragma unroll
    for (int mt = 0; mt < 2; ++mt)
        #pragma unroll
        for (int nt = 0; nt < 2; ++nt) {
            const int d = n0 + wn * 32 + nt * 16 + i16;
            const float bb = nt ? bv1 : bv0;
            ushort4 w;
            w.x = f2bs(av[mt][nt][0] + bb);
            w.y = f2bs(av[mt][nt][1] + bb);
            w.z = f2bs(av[mt][nt][2] + bb);
            w.w = f2bs(av[mt][nt][3] + bb);
            const int l = l0 + wm * 32 + mt * 16 + g * 4;
            *(ushort4*)&Vt[vtbase + (size_t)d * L_ + l] = w;
        }
    __syncthreads();
    #pragma unroll
    for (int mt = 0; mt < 2; ++mt)
        #pragma unroll
        for (int nt = 0; nt < 2; ++nt) {
            const float bb = nt ? bk1 : bk0;
            #pragma unroll
            for (int r = 0; r < 4; ++r)
                LTo[wm * 32 + mt * 16 + g * 4 + r][wn * 32 + nt * 16 + i16] =
                    f2bs(ak[mt][nt][r] + bb);
        }
    __syncthreads();
    #pragma unroll
    for (int rep = 0; rep < 2; ++rep) {
        const int m = (t >> 3) + rep * 32;
        const int cs = (t & 7) * 8;
        *(short8_t*)&Kout[(size_t)(m0 + m) * C_ + n0 + cs] = *(short8_t*)&LTo[m][cs];
    }
}

// ---------------------------------------------------------------------------
// attn v2.1 (swapped-QK MFMA): as R3 but K granules XOR-swizzled
// (gran ^= (row>>1)&3 at stage-source and read) so the QK^T A-frag
// ds_read_b128 is 2-way (free) instead of 8-way bank-conflicted.
// LDS 32 KB: K [256 rows][64 B] swizzled | V^T [32][512 B] granule-swizzled;
// Ph [64][256 B] aliases K after softmax.
// ---------------------------------------------------------------------------
__global__ __launch_bounds__(256) void attn_kernel(
    const u16* __restrict__ Qws, const u16* __restrict__ Kws,
    const u16* __restrict__ Vws, const float* __restrict__ feature,
    float* __restrict__ out)
{
    __shared__ __align__(16) unsigned char smem[32768];

    const int t = threadIdx.x;
    const int wid = t >> 6, lane = t & 63;
    const int i16 = lane & 15, g = lane >> 4;
    const int pt = blockIdx.x, h = blockIdx.y, n = blockIdx.z;
    const int pos0 = pt * 64;
    const size_t qbase = ((size_t)n * HW_ + pos0) * C_ + h * DH_;
    const size_t kbase = ((size_t)n * L_) * C_ + h * DH_;
    const size_t vbase = (size_t)n * C_ * L_ + (size_t)h * DH_ * L_;

    const int q = wid * 16 + i16;

    // Q b-frag: one 16B global load per lane
    short8_t bq = *(const short8_t*)&Qws[qbase + (size_t)q * C_ + g * 8];

    // stage K (granule-swizzled source) + V^T (granule-swizzled source)
    #pragma unroll
    for (int p = 0; p < 4; ++p) {
        const int kr = wid * 64 + p * 16 + (lane >> 2);
        const int kg = (lane & 3) ^ ((lane >> 3) & 3);   // ^= (kr>>1)&3
        const u16* ksrc = Kws + kbase + (size_t)kr * C_ + kg * 8;
        __builtin_amdgcn_global_load_lds(
            (const __attribute__((address_space(1))) void*)ksrc,
            (__attribute__((address_space(3))) void*)(smem + wid * 4096 + p * 1024),
            16, 0, 0);
        const int vd = wid * 8 + p * 2 + (lane >> 5);
        const u16* vsrc = Vws + vbase + (size_t)vd * L_ + ((lane & 31) ^ (vd & 7)) * 8;
        __builtin_amdgcn_global_load_lds(
            (const __attribute__((address_space(1))) void*)vsrc,
            (__attribute__((address_space(3))) void*)(smem + 16384 + wid * 4096 + p * 1024),
            16, 0, 0);
    }
    __syncthreads();

    // QK^T swapped: s[nf] rows = l = nf*16 + g*4 + r, col = q (lane i16)
    const int kgr = g ^ ((i16 >> 1) & 3);   // read-side K granule unswizzle
    f32x4 s[16];
    #pragma unroll
    for (int nf = 0; nf < 16; ++nf) {
        short8_t a = *(const short8_t*)(smem + (nf * 16 + i16) * 64 + kgr * 16);
        f32x4 z = {0.f, 0.f, 0.f, 0.f};
        s[nf] = __builtin_amdgcn_mfma_f32_16x16x32_bf16(a, bq, z, 0, 0, 0);
    }

    // softmax over l for fixed q: in-lane tree + cross-g shuffles
    float mm[16], sm[16];
    #pragma unroll
    for (int nf = 0; nf < 16; ++nf)
        mm[nf] = fmaxf(fmaxf(s[nf][0], s[nf][1]), fmaxf(s[nf][2], s[nf][3]));
    #pragma unroll
    for (int st = 8; st >= 1; st >>= 1)
        #pragma unroll
        for (int i = 0; i < 8; ++i)
            if (i < st) mm[i] = fmaxf(mm[i], mm[i + st]);
    float m = mm[0];
    m = fmaxf(m, __shfl_xor(m, 16));
    m = fmaxf(m, __shfl_xor(m, 32));

    const float K2 = 0.25506288f;  // log2(e) / sqrt(32)
    #pragma unroll
    for (int nf = 0; nf < 16; ++nf) {
        #pragma unroll
        for (int r = 0; r < 4; ++r) s[nf][r] = exp2f((s[nf][r] - m) * K2);
        sm[nf] = (s[nf][0] + s[nf][1]) + (s[nf][2] + s[nf][3]);
    }
    #pragma unroll
    for (int st = 8; st >= 1; st >>= 1)
        #pragma unroll
        for (int i = 0; i < 8; ++i)
            if (i < st) sm[i] += sm[i + st];
    float ssum = sm[0];
    ssum += __shfl_xor(ssum, 16);
    ssum += __shfl_xor(ssum, 32);
    const float pinv = 1.0f / ssum;

    __syncthreads();  // Kh dead -> Ph may alias

    f32x4 o0 = {0.f, 0.f, 0.f, 0.f}, o1 = {0.f, 0.f, 0.f, 0.f};
    const int e7 = i16 & 7;

    #pragma unroll
    for (int hb = 0; hb < 2; ++hb) {
        // write P half: pairs (l even) packed via v_cvt_pk_bf16_f32
        #pragma unroll
        for (int nfp = 0; nfp < 8; ++nfp) {
            const int nf = hb * 8 + nfp;
            #pragma unroll
            for (int w = 0; w < 2; ++w) {
                u32 pw = cvt_pk_bf16(s[nf][2 * w] * pinv, s[nf][2 * w + 1] * pinv);
                const int gran = (nfp * 2 + (g >> 1)) ^ e7;
                *(u32*)(smem + q * 256 + gran * 16 + ((g & 1) * 2 + w) * 4) = pw;
            }
        }
        __syncthreads();
        // PV quarter-chunks ks (l = (hb*4+ks)*32 + g*8 ..)
        #pragma unroll
        for (int ks = 0; ks < 4; ++ks) {
            short8_t pb = *(const short8_t*)(smem + q * 256 + (((ks * 4 + g) ^ e7) * 16));
            const int vg = (((hb * 4 + ks) * 4 + g) ^ e7) * 16;
            short8_t va0 = *(const short8_t*)(smem + 16384 + i16 * 512 + vg);
            short8_t va1 = *(const short8_t*)(smem + 16384 + (16 + i16) * 512 + vg);
            o0 = __builtin_amdgcn_mfma_f32_16x16x32_bf16(va0, pb, o0, 0, 0, 0);
            o1 = __builtin_amdgcn_mfma_f32_16x16x32_bf16(va1, pb, o1, 0, 0, 0);
        }
        if (hb == 0) __syncthreads();
    }

    // epilogue: lane col=q, rows d = g*4+r (+16); coalesced 64B segments
    const size_t obase = ((size_t)n * C_ + h * DH_) * HW_ + pos0 + q;
    #pragma unroll
    for (int r = 0; r < 4; ++r) {
        const size_t oa = obase + (size_t)(g * 4 + r) * HW_;
        out[oa] = feature[oa] + o0[r];
        const size_t ob = obase + (size_t)(16 + g * 4 + r) * HW_;
        out[ob] = feature[ob] + o1[r];
    }
}

extern "C" void kernel_launch(void* const* d_in, const int* in_sizes, int n_in,
                              void* d_out, int out_size, void* d_ws, size_t ws_size,
                              hipStream_t stream)
{
    const float* feature = (const float*)d_in[0];
    const float* token   = (const float*)d_in[1];
    const float* wq      = (const float*)d_in[2];
    const float* bq      = (const float*)d_in[3];
    const float* wk      = (const float*)d_in[4];
    const float* bk      = (const float*)d_in[5];
    const float* wv      = (const float*)d_in[6];
    const float* bv      = (const float*)d_in[7];
    float* out = (float*)d_out;

    // ws: Q [16384][512] bf16 (16 MiB) | K [4096][512] (4 MiB) | Vt [n][d][l] (4 MiB)
    u16* Qws = (u16*)d_ws;
    u16* Kws = Qws + (size_t)N_ * HW_ * C_;
    u16* Vws = Kws + (size_t)N_ * L_ * C_;

    // d_out doubles as scratch before attn overwrites it (33.5 MB):
    //   [16M,20M): token bf16 | [20M,21.5M): wq/wk/wv bf16
    char* ob = (char*)d_out;
    u16* tokb = (u16*)(ob + (16u << 20));
    u16* wqb  = (u16*)(ob + (20u << 20));
    u16* wkb  = (u16*)(ob + (20u << 20) + 524288);
    u16* wvb  = (u16*)(ob + (20u << 20) + 1048576);

    prep_kernel<<<dim3(2816), 256, 0, stream>>>(token, wq, wk, wv,
                                                tokb, wqb, wkb, wvb);
    gemm_qf_kernel<<<dim3(256, 8), 256, 0, stream>>>(feature, wqb, bq, Qws);
    gemm_kv_kernel<<<dim3(64, 8), 256, 0, stream>>>(tokb, wkb, wvb, bk, bv,
                                                    Kws, Vws);
    attn_kernel<<<dim3(16, 16, 16), 256, 0, stream>>>(Qws, Kws, Vws, feature, out);
}